// Round 19
// baseline (46.044 us; speedup 1.0000x reference)
//
#include <hip/hip_runtime.h>
#include <hip/hip_fp16.h>

#define H    256
#define W    256
#define WH   129            // W/2 + 1
#define VLEN 182            // max radial bin + 1
#define NIMG 64             // 32 pred + 32 target
#define TWO_PI 6.283185307179586f
#define ZSTR 516            // zbuf row stride in floats

typedef __attribute__((ext_vector_type(2))) unsigned uint2v;

// Integer-exact floor(sqrt) for s2 <= 32768: v_sqrt_f32 trunc off by <=1;
// two branchless fixups.
__device__ __forceinline__ int isqrt_fast(int s2) {
    int r = (int)__builtin_amdgcn_sqrtf((float)s2);
    r -= (r * r > s2);
    r += ((r + 1) * (r + 1) <= s2);
    return r;
}

__device__ __forceinline__ float2 cmul(float2 a, float2 b) {
    return make_float2(a.x * b.x - a.y * b.y, a.x * b.y + a.y * b.x);
}

// 256-point DIF FFT held by one 64-lane wave; thread t owns positions
// i = t + 64r (r=0..3). On exit, position i holds X[bitrev8(i)].
// hm=32/16 exchanges use VALU permlane*_swap (gfx950) instead of DS shuffles.
__device__ __forceinline__ void wfft256(float2 z[4], int t) {
    float s, c;
    // m=256: reg pairs (0,2),(1,3); w = e^{-2pi i t/256}, pair(1,3) gets w*(-i)
    __sincosf(-TWO_PI * (1.0f / 256.0f) * (float)t, &s, &c);
    {
        const float2 w0 = make_float2(c, s);
        const float2 w1 = make_float2(s, -c);          // w0 * (-i)
        float2 u0 = z[0], v0 = z[2], u1 = z[1], v1 = z[3];
        z[0] = make_float2(u0.x + v0.x, u0.y + v0.y);
        z[2] = cmul(make_float2(u0.x - v0.x, u0.y - v0.y), w0);
        z[1] = make_float2(u1.x + v1.x, u1.y + v1.y);
        z[3] = cmul(make_float2(u1.x - v1.x, u1.y - v1.y), w1);
    }
    // m=128: reg pairs (0,1),(2,3); w = e^{-2pi i t/128}
    __sincosf(-TWO_PI * (1.0f / 128.0f) * (float)t, &s, &c);
    {
        const float2 w = make_float2(c, s);
        float2 u0 = z[0], v0 = z[1], u1 = z[2], v1 = z[3];
        z[0] = make_float2(u0.x + v0.x, u0.y + v0.y);
        z[1] = cmul(make_float2(u0.x - v0.x, u0.y - v0.y), w);
        z[2] = make_float2(u1.x + v1.x, u1.y + v1.y);
        z[3] = cmul(make_float2(u1.x - v1.x, u1.y - v1.y), w);
    }
    // m=64: hm=32 exchange via v_permlane32_swap (VALU, not DS)
    {
        __sincosf((-TWO_PI / 64.0f) * (float)(t & 31), &s, &c);
        const float2 w = make_float2(c, s);
        const bool hi = (t & 32) != 0;
        #pragma unroll
        for (int r = 0; r < 4; ++r) {
            const uint2v px = __builtin_amdgcn_permlane32_swap(
                __builtin_bit_cast(unsigned, z[r].x),
                __builtin_bit_cast(unsigned, z[r].x), false, false);
            const uint2v py = __builtin_amdgcn_permlane32_swap(
                __builtin_bit_cast(unsigned, z[r].y),
                __builtin_bit_cast(unsigned, z[r].y), false, false);
            const float ox = __builtin_bit_cast(float, hi ? px[0] : px[1]);
            const float oy = __builtin_bit_cast(float, hi ? py[0] : py[1]);
            if (hi) z[r] = cmul(make_float2(ox - z[r].x, oy - z[r].y), w);
            else    z[r] = make_float2(z[r].x + ox, z[r].y + oy);
        }
    }
    // m=32: hm=16 exchange via v_permlane16_swap (VALU, not DS)
    {
        __sincosf((-TWO_PI / 32.0f) * (float)(t & 15), &s, &c);
        const float2 w = make_float2(c, s);
        const bool hi = (t & 16) != 0;
        #pragma unroll
        for (int r = 0; r < 4; ++r) {
            const uint2v px = __builtin_amdgcn_permlane16_swap(
                __builtin_bit_cast(unsigned, z[r].x),
                __builtin_bit_cast(unsigned, z[r].x), false, false);
            const uint2v py = __builtin_amdgcn_permlane16_swap(
                __builtin_bit_cast(unsigned, z[r].y),
                __builtin_bit_cast(unsigned, z[r].y), false, false);
            const float ox = __builtin_bit_cast(float, hi ? px[0] : px[1]);
            const float oy = __builtin_bit_cast(float, hi ? py[0] : py[1]);
            if (hi) z[r] = cmul(make_float2(ox - z[r].x, oy - z[r].y), w);
            else    z[r] = make_float2(z[r].x + ox, z[r].y + oy);
        }
    }
    // m=16..8: lane-xor m/2 via DS shuffle, w = e^{-2pi i (t&(m/2-1))/m}
    #pragma unroll
    for (int m = 16; m >= 8; m >>= 1) {
        const int hm = m >> 1;
        __sincosf((-TWO_PI / (float)m) * (float)(t & (hm - 1)), &s, &c);
        const float2 w = make_float2(c, s);
        const bool hi = (t & hm) != 0;
        #pragma unroll
        for (int r = 0; r < 4; ++r) {
            float2 o;
            o.x = __shfl_xor(z[r].x, hm, 64);
            o.y = __shfl_xor(z[r].y, hm, 64);
            if (hi) z[r] = cmul(make_float2(o.x - z[r].x, o.y - z[r].y), w);
            else    z[r] = make_float2(z[r].x + o.x, z[r].y + o.y);
        }
    }
    // m=4: lane-xor 2; w = 1 (t even) or -i (t odd)
    {
        const bool hi  = (t & 2) != 0;
        const bool odd = (t & 1) != 0;
        #pragma unroll
        for (int r = 0; r < 4; ++r) {
            float2 o;
            o.x = __shfl_xor(z[r].x, 2, 64);
            o.y = __shfl_xor(z[r].y, 2, 64);
            float2 d = hi ? make_float2(o.x - z[r].x, o.y - z[r].y)
                          : make_float2(z[r].x + o.x, z[r].y + o.y);
            if (hi && odd) d = make_float2(d.y, -d.x);   // * (-i)
            z[r] = d;
        }
    }
    // m=2: lane-xor 1
    {
        const bool hi = (t & 1) != 0;
        #pragma unroll
        for (int r = 0; r < 4; ++r) {
            float2 o;
            o.x = __shfl_xor(z[r].x, 1, 64);
            o.y = __shfl_xor(z[r].y, 1, 64);
            z[r] = hi ? make_float2(o.x - z[r].x, o.y - z[r].y)
                      : make_float2(z[r].x + o.x, z[r].y + o.y);
        }
    }
}

// 16 waves/block, 512 blocks = 2 dispatch rounds. XCD-pinned: img = b & 63
// (8 blocks/image, all on XCD img%8). Each wave: coalesced luma loads for a
// packed row-pair, wave FFT, per-wave LDS stash; block-cooperative unpack +
// transposed store (16 pairs per k = 128B contiguous segments).
__global__ __launch_bounds__(1024)
void rowfft_wave(const float* __restrict__ pred, const float* __restrict__ targ,
                 uint2* __restrict__ GT /* [NIMG][WH][128] uint2 = row-pair */,
                 float* __restrict__ gsum /* [NIMG][VLEN] */,
                 float* __restrict__ out) {
    __shared__ float zbuf[16][ZSTR];   // per wave: re[256] + im[256], swizzled
    const int tid  = threadIdx.x;
    const int t    = tid & 63;
    const int wid  = tid >> 6;         // 0..15
    const int b    = blockIdx.x;       // 0..511
    const int img  = b & 63;           // XCD pin: b%8 == img%8
    const int k8   = b >> 6;           // 0..7 (8 blocks per image)
    const int pair = (k8 << 4) | wid;  // 0..127
    const int rowA = pair * 2;

    if (k8 == 0) {
        if (tid < VLEN) gsum[img * VLEN + tid] = 0.0f;
    }
    if (b == 0 && tid == 0) out[0] = 0.0f;

    const float* src  = (img < 32) ? pred : targ;
    const float* base = src + (size_t)(img & 31) * (3 * H * W) + (size_t)rowA * W;

    float2 z[4];
    #pragma unroll
    for (int r = 0; r < 4; ++r) {
        const int n = t + (r << 6);
        const float aR = __builtin_nontemporal_load(base + n);
        const float aG = __builtin_nontemporal_load(base + H * W + n);
        const float aB = __builtin_nontemporal_load(base + 2 * H * W + n);
        const float bR = __builtin_nontemporal_load(base + W + n);
        const float bG = __builtin_nontemporal_load(base + H * W + W + n);
        const float bB = __builtin_nontemporal_load(base + 2 * H * W + W + n);
        z[r] = make_float2(0.299f * aR + 0.587f * aG + 0.114f * aB,
                           0.299f * bR + 0.587f * bG + 0.114f * bB);
    }

    wfft256(z, t);

    float* zr = zbuf[wid];
    float* zi = zr + 256;
    #pragma unroll
    for (int r = 0; r < 4; ++r) {
        const int x  = (int)(__brev((unsigned)(t + (r << 6))) >> 24);
        const int sx = x ^ (x >> 5);
        zr[sx] = z[r].x; zi[sx] = z[r].y;
    }
    __syncthreads();                   // all 16 waves' spectra visible

    // Block-cooperative unpack + store:
    // Ga[k] = (Z[k]+conj(Z[-k]))/2, Gb[k] = -i(Z[k]-conj(Z[-k]))/2
    uint2* dst = GT + (size_t)img * WH * 128;
    const int basePair = k8 << 4;
    for (int e = tid; e < WH * 16; e += 1024) {
        const int k  = e >> 4;
        const int lp = e & 15;
        const float* qr = zbuf[lp];
        const float* qi = qr + 256;
        const int kq = (256 - k) & 255;
        const int sk = k ^ (k >> 5), sq = kq ^ (kq >> 5);
        const float2 P = make_float2(qr[sk], qi[sk]);
        const float2 Q = make_float2(qr[sq], qi[sq]);
        const __half2 a  = __floats2half2_rn(0.5f * (P.x + Q.x), 0.5f * (P.y - Q.y));
        const __half2 bb = __floats2half2_rn(0.5f * (P.y + Q.y), 0.5f * (Q.x - P.x));
        uint2 pk;
        pk.x = __builtin_bit_cast(unsigned, a);
        pk.y = __builtin_bit_cast(unsigned, bb);
        dst[(size_t)k * 128 + basePair + lp] = pk;
    }
}

// 16 waves/block, 576 blocks. XCD-pinned: img = b & 63 (9 blocks/image).
// One column-FFT per wave; loads issued BEFORE the bins-zero barrier.
__global__ __launch_bounds__(1024)
void colfft_bin_t(const __half2* __restrict__ GT, float* __restrict__ gsum) {
    __shared__ float bins[VLEN];
    const int tid = threadIdx.x;
    const int t   = tid & 63;
    const int wid = tid >> 6;          // 0..15
    const int b   = blockIdx.x;        // 0..575
    const int img = b & 63;            // XCD pin
    const int grp = b >> 6;            // 0..8
    const int j   = grp * 16 + wid;    // 0..143

    // issue loads first; latency hides behind bins-zero + barrier
    float2 z[4];
    const bool vj = j < WH;
    if (vj) {
        const __half2* col = GT + ((size_t)img * WH + j) * 256;
        #pragma unroll
        for (int r = 0; r < 4; ++r)
            z[r] = __half22float2(col[t + (r << 6)]);
    }

    if (tid < VLEN) bins[tid] = 0.0f;
    __syncthreads();

    if (vj) {
        wfft256(z, t);

        const int j2 = j * j;
        #pragma unroll
        for (int r = 0; r < 4; ++r) {
            const int n   = (int)(__brev((unsigned)(t + (r << 6))) >> 24);
            const int di  = (n < 128) ? n : n - 256;
            const int rad = isqrt_fast(di * di + j2);
            const float p = z[r].x * z[r].x + z[r].y * z[r].y + 1e-8f;
            atomicAdd(&bins[rad], 20.0f * __logf(p));
        }
    }
    __syncthreads();

    const int j0   = grp * 16;
    const int jmax = (j0 + 15 < WH) ? j0 + 15 : WH - 1;
    const int rmax = isqrt_fast(128 * 128 + jmax * jmax);
    float* gs = gsum + (size_t)img * VLEN;
    for (int v = j0 + tid; v <= rmax; v += 1024)
        atomicAdd(&gs[v], bins[v]);
}

// 32 blocks, one per pred/target pair (block pr reads images pr and pr+32 —
// both ≡ pr mod 8, so gsum reads are XCD-local too): static bin counts,
// per-bin mean, min/max normalize, SSE partial -> atomicAdd into out.
__global__ __launch_bounds__(256)
void finish32(const float* __restrict__ gsum, float* __restrict__ out) {
    __shared__ int    scnt[VLEN];
    __shared__ float4 red4[256];
    __shared__ float  reds[256];
    const int tid = threadIdx.x;
    const int pr  = blockIdx.x;        // 0..31

    if (tid < VLEN) scnt[tid] = 0;
    __syncthreads();
    for (int e = tid; e < H * WH; e += 256) {
        const int k  = e / WH;
        const int j  = e - k * WH;
        const int di = (k < 128) ? k : k - 256;
        atomicAdd(&scnt[isqrt_fast(di * di + j * j)], 1);
    }
    __syncthreads();

    const bool val = tid < VLEN;
    float a = 0.0f, b = 0.0f;
    float4 mm = make_float4(1e30f, -1e30f, 1e30f, -1e30f);  // (min_a,max_a,min_b,max_b)
    if (val) {
        const float ic = 1.0f / (float)scnt[tid];
        a = gsum[(size_t)pr * VLEN + tid] * ic;
        b = gsum[(size_t)(pr + 32) * VLEN + tid] * ic;
        mm = make_float4(a, a, b, b);
    }
    red4[tid] = mm; __syncthreads();
    for (int off = 128; off > 0; off >>= 1) {
        if (tid < off) {
            const float4 o = red4[tid + off];
            red4[tid].x = fminf(red4[tid].x, o.x);
            red4[tid].y = fmaxf(red4[tid].y, o.y);
            red4[tid].z = fminf(red4[tid].z, o.z);
            red4[tid].w = fmaxf(red4[tid].w, o.w);
        }
        __syncthreads();
    }
    const float4 m = red4[0];
    const float inva = 1.0f / (m.y - m.x);
    const float invb = 1.0f / (m.w - m.z);
    const float d = val ? (a - m.x) * inva - (b - m.z) * invb : 0.0f;
    reds[tid] = d * d; __syncthreads();
    for (int off = 128; off > 0; off >>= 1) {
        if (tid < off) reds[tid] += reds[tid + off];
        __syncthreads();
    }
    if (tid == 0) atomicAdd(out, reds[0] * (1.0f / (float)(32 * VLEN)));
}

extern "C" void kernel_launch(void* const* d_in, const int* in_sizes, int n_in,
                              void* d_out, int out_size, void* d_ws, size_t ws_size,
                              hipStream_t stream) {
    const float* pred = (const float*)d_in[0];
    const float* targ = (const float*)d_in[1];
    float* out = (float*)d_out;

    char* ws = (char*)d_ws;
    uint2* GT = (uint2*)ws;                                      // NIMG*WH*128 uint2
    ws += (size_t)NIMG * WH * 128 * sizeof(uint2);
    float* gsum = (float*)ws;                                    // NIMG*VLEN floats

    rowfft_wave<<<512, 1024, 0, stream>>>(pred, targ, GT, gsum, out);
    colfft_bin_t<<<576, 1024, 0, stream>>>((const __half2*)GT, gsum);
    finish32<<<32, 256, 0, stream>>>(gsum, out);
}

// Round 20
// 45.747 us; speedup vs baseline: 1.0065x; 1.0065x over previous
//
#include <hip/hip_runtime.h>
#include <hip/hip_fp16.h>

#define H    256
#define W    256
#define WH   129            // W/2 + 1
#define VLEN 182            // max radial bin + 1
#define NIMG 64             // 32 pred + 32 target
#define ZSTR 516            // zbuf row stride in floats

typedef __attribute__((ext_vector_type(2))) unsigned uint2v;

// Integer-exact floor(sqrt) for s2 <= 32768: v_sqrt_f32 trunc off by <=1;
// two branchless fixups.
__device__ __forceinline__ int isqrt_fast(int s2) {
    int r = (int)__builtin_amdgcn_sqrtf((float)s2);
    r -= (r * r > s2);
    r += ((r + 1) * (r + 1) <= s2);
    return r;
}

__device__ __forceinline__ float2 cmul(float2 a, float2 b) {
    return make_float2(a.x * b.x - a.y * b.y, a.x * b.y + a.y * b.x);
}

// Twiddle e^{-2*pi*i*frac} via raw v_sin_f32/v_cos_f32 (argument in
// REVOLUTIONS per gfx950 ISA) — one instruction each, no range reduction.
// frac here is an exact power-of-2 fraction in [0,1).
__device__ __forceinline__ float2 twid(float frac) {
    const float s = __builtin_amdgcn_sinf(frac);
    const float c = __builtin_amdgcn_cosf(frac);
    return make_float2(c, -s);
}

// 256-point DIF FFT held by one 64-lane wave; thread t owns positions
// i = t + 64r (r=0..3). On exit, position i holds X[bitrev8(i)].
// hm=32/16 exchanges use VALU permlane*_swap; twiddles via hardware sin/cos.
__device__ __forceinline__ void wfft256(float2 z[4], int t) {
    // m=256: reg pairs (0,2),(1,3); w = e^{-2pi i t/256}, pair(1,3) gets w*(-i)
    {
        const float2 w0 = twid((float)t * (1.0f / 256.0f));
        const float2 w1 = make_float2(w0.y, -w0.x);    // w0 * (-i)
        float2 u0 = z[0], v0 = z[2], u1 = z[1], v1 = z[3];
        z[0] = make_float2(u0.x + v0.x, u0.y + v0.y);
        z[2] = cmul(make_float2(u0.x - v0.x, u0.y - v0.y), w0);
        z[1] = make_float2(u1.x + v1.x, u1.y + v1.y);
        z[3] = cmul(make_float2(u1.x - v1.x, u1.y - v1.y), w1);
    }
    // m=128: reg pairs (0,1),(2,3); w = e^{-2pi i t/128}
    {
        const float2 w = twid((float)t * (1.0f / 128.0f));
        float2 u0 = z[0], v0 = z[1], u1 = z[2], v1 = z[3];
        z[0] = make_float2(u0.x + v0.x, u0.y + v0.y);
        z[1] = cmul(make_float2(u0.x - v0.x, u0.y - v0.y), w);
        z[2] = make_float2(u1.x + v1.x, u1.y + v1.y);
        z[3] = cmul(make_float2(u1.x - v1.x, u1.y - v1.y), w);
    }
    // m=64: hm=32 exchange via v_permlane32_swap (VALU, not DS)
    {
        const float2 w = twid((float)(t & 31) * (1.0f / 64.0f));
        const bool hi = (t & 32) != 0;
        #pragma unroll
        for (int r = 0; r < 4; ++r) {
            const uint2v px = __builtin_amdgcn_permlane32_swap(
                __builtin_bit_cast(unsigned, z[r].x),
                __builtin_bit_cast(unsigned, z[r].x), false, false);
            const uint2v py = __builtin_amdgcn_permlane32_swap(
                __builtin_bit_cast(unsigned, z[r].y),
                __builtin_bit_cast(unsigned, z[r].y), false, false);
            const float ox = __builtin_bit_cast(float, hi ? px[0] : px[1]);
            const float oy = __builtin_bit_cast(float, hi ? py[0] : py[1]);
            if (hi) z[r] = cmul(make_float2(ox - z[r].x, oy - z[r].y), w);
            else    z[r] = make_float2(z[r].x + ox, z[r].y + oy);
        }
    }
    // m=32: hm=16 exchange via v_permlane16_swap (VALU, not DS)
    {
        const float2 w = twid((float)(t & 15) * (1.0f / 32.0f));
        const bool hi = (t & 16) != 0;
        #pragma unroll
        for (int r = 0; r < 4; ++r) {
            const uint2v px = __builtin_amdgcn_permlane16_swap(
                __builtin_bit_cast(unsigned, z[r].x),
                __builtin_bit_cast(unsigned, z[r].x), false, false);
            const uint2v py = __builtin_amdgcn_permlane16_swap(
                __builtin_bit_cast(unsigned, z[r].y),
                __builtin_bit_cast(unsigned, z[r].y), false, false);
            const float ox = __builtin_bit_cast(float, hi ? px[0] : px[1]);
            const float oy = __builtin_bit_cast(float, hi ? py[0] : py[1]);
            if (hi) z[r] = cmul(make_float2(ox - z[r].x, oy - z[r].y), w);
            else    z[r] = make_float2(z[r].x + ox, z[r].y + oy);
        }
    }
    // m=16: lane-xor 8 via DS shuffle
    {
        const float2 w = twid((float)(t & 7) * (1.0f / 16.0f));
        const bool hi = (t & 8) != 0;
        #pragma unroll
        for (int r = 0; r < 4; ++r) {
            float2 o;
            o.x = __shfl_xor(z[r].x, 8, 64);
            o.y = __shfl_xor(z[r].y, 8, 64);
            if (hi) z[r] = cmul(make_float2(o.x - z[r].x, o.y - z[r].y), w);
            else    z[r] = make_float2(z[r].x + o.x, z[r].y + o.y);
        }
    }
    // m=8: lane-xor 4 via DS shuffle
    {
        const float2 w = twid((float)(t & 3) * (1.0f / 8.0f));
        const bool hi = (t & 4) != 0;
        #pragma unroll
        for (int r = 0; r < 4; ++r) {
            float2 o;
            o.x = __shfl_xor(z[r].x, 4, 64);
            o.y = __shfl_xor(z[r].y, 4, 64);
            if (hi) z[r] = cmul(make_float2(o.x - z[r].x, o.y - z[r].y), w);
            else    z[r] = make_float2(z[r].x + o.x, z[r].y + o.y);
        }
    }
    // m=4: lane-xor 2; w = 1 (t even) or -i (t odd)
    {
        const bool hi  = (t & 2) != 0;
        const bool odd = (t & 1) != 0;
        #pragma unroll
        for (int r = 0; r < 4; ++r) {
            float2 o;
            o.x = __shfl_xor(z[r].x, 2, 64);
            o.y = __shfl_xor(z[r].y, 2, 64);
            float2 d = hi ? make_float2(o.x - z[r].x, o.y - z[r].y)
                          : make_float2(z[r].x + o.x, z[r].y + o.y);
            if (hi && odd) d = make_float2(d.y, -d.x);   // * (-i)
            z[r] = d;
        }
    }
    // m=2: lane-xor 1
    {
        const bool hi = (t & 1) != 0;
        #pragma unroll
        for (int r = 0; r < 4; ++r) {
            float2 o;
            o.x = __shfl_xor(z[r].x, 1, 64);
            o.y = __shfl_xor(z[r].y, 1, 64);
            z[r] = hi ? make_float2(o.x - z[r].x, o.y - z[r].y)
                      : make_float2(z[r].x + o.x, z[r].y + o.y);
        }
    }
}

// 8 waves/block. XCD-pinned block mapping: img = b & 63 (so all of image
// i's blocks land on XCD i%8 under round-robin dispatch; GT[i] stays in that
// XCD's L2 for colfft). Each wave: coalesced luma loads for a packed
// row-pair, wave FFT, per-wave LDS stash; block-cooperative unpack +
// coalesced transposed store.
__global__ __launch_bounds__(512)
void rowfft_wave(const float* __restrict__ pred, const float* __restrict__ targ,
                 uint2* __restrict__ GT /* [NIMG][WH][128] uint2 = row-pair */,
                 float* __restrict__ gsum /* [NIMG][VLEN] */,
                 float* __restrict__ out) {
    __shared__ float zbuf[8][ZSTR];    // per wave: re[256] + im[256], swizzled
    const int tid  = threadIdx.x;
    const int t    = tid & 63;
    const int wid  = tid >> 6;         // 0..7
    const int b    = blockIdx.x;       // 0..1023
    const int img  = b & 63;           // XCD pin: b%8 == img%8
    const int k16  = b >> 6;           // 0..15 (16 blocks per image)
    const int pair = (k16 << 3) | wid;
    const int rowA = pair * 2;

    if (k16 == 0) {
        if (tid < VLEN) gsum[img * VLEN + tid] = 0.0f;
    }
    if (b == 0 && tid == 0) out[0] = 0.0f;

    const float* src  = (img < 32) ? pred : targ;
    const float* base = src + (size_t)(img & 31) * (3 * H * W) + (size_t)rowA * W;

    float2 z[4];
    #pragma unroll
    for (int r = 0; r < 4; ++r) {
        const int n = t + (r << 6);
        const float aR = __builtin_nontemporal_load(base + n);
        const float aG = __builtin_nontemporal_load(base + H * W + n);
        const float aB = __builtin_nontemporal_load(base + 2 * H * W + n);
        const float bR = __builtin_nontemporal_load(base + W + n);
        const float bG = __builtin_nontemporal_load(base + H * W + W + n);
        const float bB = __builtin_nontemporal_load(base + 2 * H * W + W + n);
        z[r] = make_float2(0.299f * aR + 0.587f * aG + 0.114f * aB,
                           0.299f * bR + 0.587f * bG + 0.114f * bB);
    }

    wfft256(z, t);

    float* zr = zbuf[wid];
    float* zi = zr + 256;
    #pragma unroll
    for (int r = 0; r < 4; ++r) {
        const int x  = (int)(__brev((unsigned)(t + (r << 6))) >> 24);
        const int sx = x ^ (x >> 5);
        zr[sx] = z[r].x; zi[sx] = z[r].y;
    }
    __syncthreads();                   // all 8 waves' spectra visible

    // Block-cooperative unpack + store:
    // Ga[k] = (Z[k]+conj(Z[-k]))/2, Gb[k] = -i(Z[k]-conj(Z[-k]))/2
    uint2* dst = GT + (size_t)img * WH * 128;
    const int basePair = k16 << 3;
    for (int e = tid; e < WH * 8; e += 512) {
        const int k  = e >> 3;
        const int lp = e & 7;
        const float* qr = zbuf[lp];
        const float* qi = qr + 256;
        const int kq = (256 - k) & 255;
        const int sk = k ^ (k >> 5), sq = kq ^ (kq >> 5);
        const float2 P = make_float2(qr[sk], qi[sk]);
        const float2 Q = make_float2(qr[sq], qi[sq]);
        const __half2 a  = __floats2half2_rn(0.5f * (P.x + Q.x), 0.5f * (P.y - Q.y));
        const __half2 bb = __floats2half2_rn(0.5f * (P.y + Q.y), 0.5f * (Q.x - P.x));
        uint2 pk;
        pk.x = __builtin_bit_cast(unsigned, a);
        pk.y = __builtin_bit_cast(unsigned, bb);
        dst[(size_t)k * 128 + basePair + lp] = pk;
    }
}

// 8 waves/block, one column-FFT per wave. XCD-pinned: img = b & 63, same
// mapping as rowfft, so GT[img] column loads hit the local XCD L2. Column
// loads are issued BEFORE the bins-zero barrier to hide their latency.
__global__ __launch_bounds__(512)
void colfft_bin_t(const __half2* __restrict__ GT, float* __restrict__ gsum) {
    __shared__ float bins[VLEN];
    const int tid = threadIdx.x;
    const int t   = tid & 63;
    const int wid = tid >> 6;          // 0..7
    const int b   = blockIdx.x;        // 0..NIMG*17-1
    const int img = b & 63;            // XCD pin
    const int grp = b >> 6;            // 0..16
    const int j   = grp * 8 + wid;     // 0..135

    // issue loads first; latency hides behind bins-zero + barrier
    float2 z[4];
    const bool vj = j < WH;
    if (vj) {
        const __half2* col = GT + ((size_t)img * WH + j) * 256;
        #pragma unroll
        for (int r = 0; r < 4; ++r)
            z[r] = __half22float2(col[t + (r << 6)]);
    }

    if (tid < VLEN) bins[tid] = 0.0f;
    __syncthreads();

    if (vj) {
        wfft256(z, t);

        const int j2 = j * j;
        #pragma unroll
        for (int r = 0; r < 4; ++r) {
            const int n   = (int)(__brev((unsigned)(t + (r << 6))) >> 24);
            const int di  = (n < 128) ? n : n - 256;
            const int rad = isqrt_fast(di * di + j2);
            const float p = z[r].x * z[r].x + z[r].y * z[r].y + 1e-8f;
            atomicAdd(&bins[rad], 20.0f * __logf(p));
        }
    }
    __syncthreads();

    const int j0   = grp * 8;
    const int jmax = (j0 + 7 < WH) ? j0 + 7 : WH - 1;
    const int rmax = isqrt_fast(128 * 128 + jmax * jmax);
    float* gs = gsum + (size_t)img * VLEN;
    for (int v = j0 + tid; v <= rmax; v += 512)
        atomicAdd(&gs[v], bins[v]);
}

// 32 blocks, one per pred/target pair (block pr reads images pr and pr+32 —
// both ≡ pr mod 8, so gsum reads are XCD-local too): static bin counts,
// per-bin mean, min/max normalize, SSE partial -> atomicAdd into out.
__global__ __launch_bounds__(256)
void finish32(const float* __restrict__ gsum, float* __restrict__ out) {
    __shared__ int    scnt[VLEN];
    __shared__ float4 red4[256];
    __shared__ float  reds[256];
    const int tid = threadIdx.x;
    const int pr  = blockIdx.x;        // 0..31

    if (tid < VLEN) scnt[tid] = 0;
    __syncthreads();
    for (int e = tid; e < H * WH; e += 256) {
        const int k  = e / WH;
        const int j  = e - k * WH;
        const int di = (k < 128) ? k : k - 256;
        atomicAdd(&scnt[isqrt_fast(di * di + j * j)], 1);
    }
    __syncthreads();

    const bool val = tid < VLEN;
    float a = 0.0f, b = 0.0f;
    float4 mm = make_float4(1e30f, -1e30f, 1e30f, -1e30f);  // (min_a,max_a,min_b,max_b)
    if (val) {
        const float ic = 1.0f / (float)scnt[tid];
        a = gsum[(size_t)pr * VLEN + tid] * ic;
        b = gsum[(size_t)(pr + 32) * VLEN + tid] * ic;
        mm = make_float4(a, a, b, b);
    }
    red4[tid] = mm; __syncthreads();
    for (int off = 128; off > 0; off >>= 1) {
        if (tid < off) {
            const float4 o = red4[tid + off];
            red4[tid].x = fminf(red4[tid].x, o.x);
            red4[tid].y = fmaxf(red4[tid].y, o.y);
            red4[tid].z = fminf(red4[tid].z, o.z);
            red4[tid].w = fmaxf(red4[tid].w, o.w);
        }
        __syncthreads();
    }
    const float4 m = red4[0];
    const float inva = 1.0f / (m.y - m.x);
    const float invb = 1.0f / (m.w - m.z);
    const float d = val ? (a - m.x) * inva - (b - m.z) * invb : 0.0f;
    reds[tid] = d * d; __syncthreads();
    for (int off = 128; off > 0; off >>= 1) {
        if (tid < off) reds[tid] += reds[tid + off];
        __syncthreads();
    }
    if (tid == 0) atomicAdd(out, reds[0] * (1.0f / (float)(32 * VLEN)));
}

extern "C" void kernel_launch(void* const* d_in, const int* in_sizes, int n_in,
                              void* d_out, int out_size, void* d_ws, size_t ws_size,
                              hipStream_t stream) {
    const float* pred = (const float*)d_in[0];
    const float* targ = (const float*)d_in[1];
    float* out = (float*)d_out;

    char* ws = (char*)d_ws;
    uint2* GT = (uint2*)ws;                                      // NIMG*WH*128 uint2
    ws += (size_t)NIMG * WH * 128 * sizeof(uint2);
    float* gsum = (float*)ws;                                    // NIMG*VLEN floats

    rowfft_wave<<<NIMG * 16, 512, 0, stream>>>(pred, targ, GT, gsum, out);
    colfft_bin_t<<<NIMG * 17, 512, 0, stream>>>((const __half2*)GT, gsum);
    finish32<<<32, 256, 0, stream>>>(gsum, out);
}